// Round 1
// baseline (51.455 us; speedup 1.0000x reference)
//
#include <hip/hip_runtime.h>

// SeMCA fused implementation.
// Sizes: bs=2, C=64, IMG=21, D=441, P=25, PAD1=220.
// ws layout (floats): k1[2][441][64], v[2][64][441], windowT[2][25][64][64]

#define BVO 28224   // 64*441 per-batch offset

// ---------------- Kernel 1: k1 (depthwise "conv1d" over channel axis) + v (depthwise 3x3) ----
__global__ __launch_bounds__(64) void prep_kernel(
    const float* __restrict__ x, const float* __restrict__ wk, const float* __restrict__ bk,
    const float* __restrict__ wv, const float* __restrict__ bv,
    float* __restrict__ k1, float* __restrict__ v)
{
    int blk = blockIdx.x;
    int tid = threadIdx.x;
    if (blk < 882) {
        // k1[b,d,c] = bk[d] + sum_{cp} x[b,cp,d] * wk[d, cp - c + 220]
        int b = blk / 441, d = blk % 441;
        __shared__ float sx[64];
        __shared__ float swk[127];
        sx[tid]  = x[b*BVO + tid*441 + d];
        swk[tid] = wk[d*441 + 157 + tid];
        if (tid < 63) swk[64 + tid] = wk[d*441 + 221 + tid];
        __syncthreads();
        float acc = bk[d];
        #pragma unroll
        for (int cp = 0; cp < 64; ++cp)
            acc += sx[cp] * swk[cp + 63 - tid];
        k1[b*BVO + d*64 + tid] = acc;
    } else {
        // depthwise 3x3 conv, pad 1
        int idx = blk - 882;              // [0,128)
        int b = idx >> 6, cv = idx & 63;
        float w[9];
        #pragma unroll
        for (int t = 0; t < 9; ++t) w[t] = wv[cv*9 + t];
        float bias = bv[cv];
        const float* xp = x + b*BVO + cv*441;
        for (int pos = tid; pos < 441; pos += 64) {
            int y = pos / 21, xx = pos % 21;
            float acc = bias;
            #pragma unroll
            for (int ky = 0; ky < 3; ++ky) {
                int yy = y + ky - 1;
                if (yy < 0 || yy >= 21) continue;
                #pragma unroll
                for (int kx = 0; kx < 3; ++kx) {
                    int xc = xx + kx - 1;
                    if (xc < 0 || xc >= 21) continue;
                    acc += xp[yy*21 + xc] * w[ky*3 + kx];
                }
            }
            v[b*BVO + cv*441 + pos] = acc;
        }
    }
}

// ---------------- Kernel 2: per-(b,g) attention embed + online softmax + window extract ------
__global__ __launch_bounds__(512) void attn_kernel(
    const float* __restrict__ x, const float* __restrict__ k1,
    const float* __restrict__ w1,
    const float* __restrict__ bn_gamma, const float* __restrict__ bn_beta,
    const float* __restrict__ bn_mean,  const float* __restrict__ bn_var,
    const float* __restrict__ w2, const float* __restrict__ b2,
    float* __restrict__ windowT)
{
    int blk = blockIdx.x;            // 50 = 2*25
    int b = blk / 25, g = blk % 25;
    int ph = g / 5, pw = g % 5;
    int tid = threadIdx.x;

    __shared__ float kq[50][64];
    __shared__ float att1[25][64];
    __shared__ float pm[8][64];
    __shared__ float pz[8][64];
    __shared__ float sm_m[64];
    __shared__ float sm_rz[64];

    // build kq[m][e]: m<25 -> Q rows, m>=25 -> K rows
    for (int idx = tid; idx < 3200; idx += 512) {
        int m = idx >> 6, e = idx & 63;
        int B = (m < 25) ? m : (m - 25);
        int u = (B << 6) + e;            // u = 25*c + 5*i + j
        int c = u / 25;
        int rem = u - 25 * c;
        int i = rem / 5;
        int j = rem - 5 * i;
        int row = 5*i + ph, col = 5*j + pw;
        float val = 0.f;
        if (row < 21 && col < 21) {
            if (m < 25) val = x[b*BVO + c*441 + row*21 + col];
            else        val = k1[b*BVO + (row*21 + col)*64 + c];
        }
        kq[m][e] = val;
    }
    __syncthreads();

    // att1 = relu(BN(w1[g] @ kq))   (25x50 @ 50x64)
    for (int idx = tid; idx < 1600; idx += 512) {
        int o = idx >> 6, e = idx & 63;
        const float* wp = w1 + g*1250 + o*50;
        float acc = 0.f;
        #pragma unroll
        for (int m = 0; m < 50; ++m) acc += wp[m] * kq[m][e];
        float inv = bn_gamma[g*25 + o] * rsqrtf(bn_var[g*25 + o] + 1e-5f);
        acc = (acc - bn_mean[g*25 + o]) * inv + bn_beta[g*25 + o];
        att1[o][e] = fmaxf(acc, 0.f);
    }
    __syncthreads();

    // att2[o2][e] = b2 + w2[g] @ att1  (441x25 @ 25x64), online softmax over o2 per column e
    int e = tid & 63;
    int q = tid >> 6;                 // 8 partials per column
    float a1r[25];
    #pragma unroll
    for (int i = 0; i < 25; ++i) a1r[i] = att1[i][e];

    float mx = -1e30f, Z = 0.f;
    for (int o2 = q; o2 < 441; o2 += 8) {
        const float* wp = w2 + g*11025 + o2*25;
        float val = b2[g*441 + o2];
        #pragma unroll
        for (int i = 0; i < 25; ++i) val += wp[i] * a1r[i];
        float nm = fmaxf(mx, val);
        Z = Z * __expf(mx - nm) + __expf(val - nm);
        mx = nm;
    }
    pm[q][e] = mx; pz[q][e] = Z;
    __syncthreads();
    if (tid < 64) {
        float M = -1e30f;
        #pragma unroll
        for (int qq = 0; qq < 8; ++qq) M = fmaxf(M, pm[qq][tid]);
        float Zs = 0.f;
        #pragma unroll
        for (int qq = 0; qq < 8; ++qq) Zs += pz[qq][tid] * __expf(pm[qq][tid] - M);
        sm_m[tid]  = M;
        sm_rz[tid] = 1.f / Zs;
    }
    __syncthreads();

    // window: only o2 = cv + 220 - e (cv in [0,64)) is ever consumed downstream
    float* wout = windowT + (b*25 + g) * 4096;
    for (int idx = tid; idx < 4096; idx += 512) {
        int cv = idx >> 6, ee = idx & 63;
        int o2 = cv + 220 - ee;
        const float* wp = w2 + g*11025 + o2*25;
        float val = b2[g*441 + o2];
        #pragma unroll
        for (int i = 0; i < 25; ++i) val += wp[i] * att1[i][ee];
        wout[idx] = __expf(val - sm_m[ee]) * sm_rz[ee];
    }
}

// ---------------- Kernel 3: out[b,e,y,x] = k1_pad + sum_cv v[b,cv,y-2,x-2]*windowT[b,g,cv,e] --
__global__ __launch_bounds__(64) void out_kernel(
    const float* __restrict__ k1, const float* __restrict__ v,
    const float* __restrict__ windowT, float* __restrict__ out)
{
    int blk = blockIdx.x;            // 882 = 2*441
    int b = blk / 441, pos = blk % 441;
    int y = pos / 21, xx = pos % 21;
    int R = y + 2, Cc = xx + 2;
    int g = 5 * (R % 5) + (Cc % 5);
    int e = threadIdx.x;

    float kt = 0.f;
    if (R < 21 && Cc < 21) kt = k1[b*BVO + (R*21 + Cc)*64 + e];

    float vt = 0.f;
    __shared__ float sv[64];
    if (y >= 2 && xx >= 2) {               // block-uniform branch
        sv[e] = v[b*BVO + e*441 + (y-2)*21 + (xx-2)];
        __syncthreads();
        const float* wp = windowT + (b*25 + g)*4096 + e;
        #pragma unroll
        for (int cv = 0; cv < 64; ++cv) vt += sv[cv] * wp[cv*64];
    }
    out[b*BVO + e*441 + pos] = kt + vt;
}

extern "C" void kernel_launch(void* const* d_in, const int* in_sizes, int n_in,
                              void* d_out, int out_size, void* d_ws, size_t ws_size,
                              hipStream_t stream) {
    const float* x        = (const float*)d_in[0];
    const float* wk       = (const float*)d_in[1];
    const float* bk       = (const float*)d_in[2];
    const float* w1       = (const float*)d_in[3];
    const float* bn_gamma = (const float*)d_in[4];
    const float* bn_beta  = (const float*)d_in[5];
    const float* bn_mean  = (const float*)d_in[6];
    const float* bn_var   = (const float*)d_in[7];
    const float* w2       = (const float*)d_in[8];
    const float* b2       = (const float*)d_in[9];
    const float* wv       = (const float*)d_in[10];
    const float* bv       = (const float*)d_in[11];

    float* out     = (float*)d_out;
    float* k1      = (float*)d_ws;           // 56448 floats
    float* v       = k1 + 56448;             // 56448 floats
    float* windowT = v + 56448;              // 204800 floats

    hipLaunchKernelGGL(prep_kernel, dim3(1010), dim3(64), 0, stream,
                       x, wk, bk, wv, bv, k1, v);
    hipLaunchKernelGGL(attn_kernel, dim3(50), dim3(512), 0, stream,
                       x, k1, w1, bn_gamma, bn_beta, bn_mean, bn_var, w2, b2, windowT);
    hipLaunchKernelGGL(out_kernel, dim3(882), dim3(64), 0, stream,
                       k1, v, windowT, out);
}

// Round 2
// 38.989 us; speedup vs baseline: 1.3197x; 1.3197x over previous
//
#include <hip/hip_runtime.h>

// SeMCA fused implementation, v2 (latency-oriented restructure).
// Sizes: bs=2, C=64, IMG=21, D=441, P=25, PAD1=220.
#define BVO 28224   // 64*441 per-batch offset
#define RPC 56      // o2 rows per chunk (8 chunks, last has 49 valid)

// ws layout (floats):
//  k1     [2][441][64]        56448
//  v      [2][64][441]        56448
//  att1g  [2][25][25][64]     80000
//  att2c  [2][25][127][64]   406400   (rows o2 in [157,284))
//  pm     [2][25][8][64]      25600
//  pz     [2][25][8][64]      25600

// ---------------- Kernel 1: k1 (depthwise conv over channel axis) + v (depthwise 3x3) ----
__global__ __launch_bounds__(64) void prep_kernel(
    const float* __restrict__ x, const float* __restrict__ wk, const float* __restrict__ bk,
    const float* __restrict__ wv, const float* __restrict__ bv,
    float* __restrict__ k1, float* __restrict__ v)
{
    int blk = blockIdx.x;
    int tid = threadIdx.x;
    if (blk < 882) {
        // k1[b,d,c] = bk[d] + sum_{cp} x[b,cp,d] * wk[d, cp - c + 220]
        int b = blk / 441, d = blk % 441;
        __shared__ float sx[64];
        __shared__ float swk[127];
        sx[tid]  = x[b*BVO + tid*441 + d];
        swk[tid] = wk[d*441 + 157 + tid];
        if (tid < 63) swk[64 + tid] = wk[d*441 + 221 + tid];
        __syncthreads();
        float acc = bk[d];
        #pragma unroll
        for (int cp = 0; cp < 64; ++cp)
            acc += sx[cp] * swk[cp + 63 - tid];
        k1[b*BVO + d*64 + tid] = acc;
    } else {
        // depthwise 3x3 conv, pad 1
        int idx = blk - 882;              // [0,128)
        int b = idx >> 6, cv = idx & 63;
        float w[9];
        #pragma unroll
        for (int t = 0; t < 9; ++t) w[t] = wv[cv*9 + t];
        float bias = bv[cv];
        const float* xp = x + b*BVO + cv*441;
        for (int pos = tid; pos < 441; pos += 64) {
            int y = pos / 21, xx = pos % 21;
            float acc = bias;
            #pragma unroll
            for (int ky = 0; ky < 3; ++ky) {
                int yy = y + ky - 1;
                if (yy < 0 || yy >= 21) continue;
                #pragma unroll
                for (int kx = 0; kx < 3; ++kx) {
                    int xc = xx + kx - 1;
                    if (xc < 0 || xc >= 21) continue;
                    acc += xp[yy*21 + xc] * w[ky*3 + kx];
                }
            }
            v[b*BVO + cv*441 + pos] = acc;
        }
    }
}

// ---------------- Kernel 2: att1 = relu(BN(w1[g] @ kq))  ->  ws  -----------------------
__global__ __launch_bounds__(256) void att1_kernel(
    const float* __restrict__ x, const float* __restrict__ k1,
    const float* __restrict__ w1,
    const float* __restrict__ bn_gamma, const float* __restrict__ bn_beta,
    const float* __restrict__ bn_mean,  const float* __restrict__ bn_var,
    float* __restrict__ att1g)
{
    int blk = blockIdx.x;            // 50 = 2*25
    int b = blk / 25, g = blk % 25;
    int ph = g / 5, pw = g % 5;
    int tid = threadIdx.x;

    __shared__ float kq[50][64];
    __shared__ float w1s[1250];

    for (int idx = tid; idx < 1250; idx += 256) w1s[idx] = w1[g*1250 + idx];

    for (int idx = tid; idx < 3200; idx += 256) {
        int m = idx >> 6, e = idx & 63;
        int B = (m < 25) ? m : (m - 25);
        int u = (B << 6) + e;            // u = 25*c + 5*i + j
        int c = u / 25;
        int rem = u - 25 * c;
        int i = rem / 5;
        int j = rem - 5 * i;
        int row = 5*i + ph, col = 5*j + pw;
        float val = 0.f;
        if (row < 21 && col < 21) {
            if (m < 25) val = x[b*BVO + c*441 + row*21 + col];
            else        val = k1[b*BVO + (row*21 + col)*64 + c];
        }
        kq[m][e] = val;
    }
    __syncthreads();

    for (int idx = tid; idx < 1600; idx += 256) {
        int o = idx >> 6, e = idx & 63;
        float acc = 0.f;
        #pragma unroll
        for (int m = 0; m < 50; ++m) acc += w1s[o*50 + m] * kq[m][e];
        float inv = bn_gamma[g*25 + o] * rsqrtf(bn_var[g*25 + o] + 1e-5f);
        acc = (acc - bn_mean[g*25 + o]) * inv + bn_beta[g*25 + o];
        att1g[blk*1600 + idx] = fmaxf(acc, 0.f);
    }
}

// ---------------- Kernel 3: att2 rows (chunked) + partial softmax stats ----------------
__global__ __launch_bounds__(256) void att2_kernel(
    const float* __restrict__ att1g, const float* __restrict__ w2,
    const float* __restrict__ b2,
    float* __restrict__ att2c, float* __restrict__ pm, float* __restrict__ pz)
{
    int blk = blockIdx.x;            // 400 = (b*25+g)*8 + ch
    int ch = blk & 7;
    int bg = blk >> 3;
    int g  = bg % 25;
    int tid = threadIdx.x;
    int e = tid & 63;
    int q = tid >> 6;                // wave id (4 waves)

    __shared__ float a1[1600];       // [i][e] flat
    __shared__ float red[4][64];

    for (int idx = tid; idx < 1600; idx += 256)
        a1[idx] = att1g[bg*1600 + idx];
    __syncthreads();

    float a1r[25];
    #pragma unroll
    for (int i = 0; i < 25; ++i) a1r[i] = a1[i*64 + e];

    int qb = __builtin_amdgcn_readfirstlane(q);   // force wave-uniform -> scalar loads
    int base = ch * RPC + qb;

    float vals[14];
    float mx = -1e30f;
    #pragma unroll
    for (int r = 0; r < 14; ++r) {
        int o2 = base + 4*r;
        int o2c = (o2 < 441) ? o2 : 440;          // clamp for safe (scalar) load
        const float* wp = w2 + g*11025 + o2c*25;
        float acc = b2[g*441 + o2c];
        #pragma unroll
        for (int i = 0; i < 25; ++i) acc += wp[i] * a1r[i];
        vals[r] = (o2 < 441) ? acc : -1e30f;
        mx = fmaxf(mx, vals[r]);
        if (o2 >= 157 && o2 < 284)                // only rows the window consumes
            att2c[(bg*127 + (o2 - 157))*64 + e] = acc;
    }

    red[q][e] = mx;
    __syncthreads();
    float m4 = fmaxf(fmaxf(red[0][e], red[1][e]), fmaxf(red[2][e], red[3][e]));
    float z = 0.f;
    #pragma unroll
    for (int r = 0; r < 14; ++r) z += __expf(vals[r] - m4);
    __syncthreads();
    red[q][e] = z;
    __syncthreads();
    if (q == 0) {
        float zs = red[0][e] + red[1][e] + red[2][e] + red[3][e];
        pm[bg*512 + ch*64 + e] = m4;
        pz[bg*512 + ch*64 + e] = zs;
    }
}

// ---------------- Kernel 4: finalize stats + window weights + output -------------------
__global__ __launch_bounds__(256) void out_kernel(
    const float* __restrict__ k1, const float* __restrict__ v,
    const float* __restrict__ att2c,
    const float* __restrict__ pm, const float* __restrict__ pz,
    float* __restrict__ out)
{
    int blk = blockIdx.x;            // 50 = b*25+g
    int b = blk / 25, g = blk % 25;
    int tid = threadIdx.x;
    int e  = tid & 63;
    int ps = tid >> 6;

    __shared__ float a2[127*64];     // 32.5 KB
    __shared__ float wT[64*64];      // 16 KB, wT[cv][e]
    __shared__ float smM[64], smR[64];
    __shared__ float sv[4][64];

    if (tid < 64) {
        float M = -1e30f;
        #pragma unroll
        for (int c = 0; c < 8; ++c) M = fmaxf(M, pm[blk*512 + c*64 + tid]);
        float Z = 0.f;
        #pragma unroll
        for (int c = 0; c < 8; ++c)
            Z += pz[blk*512 + c*64 + tid] * __expf(pm[blk*512 + c*64 + tid] - M);
        smM[tid] = M;
        smR[tid] = 1.f / Z;
    }
    for (int idx = tid; idx < 8128; idx += 256)
        a2[idx] = att2c[blk*8128 + idx];
    __syncthreads();

    // window weights: wT[cv][e] = softmax(att2)[o2 = cv+220-e][e]
    for (int idx = tid; idx < 4096; idx += 256) {
        int cv = idx >> 6, ee = idx & 63;
        wT[idx] = __expf(a2[(cv + 63 - ee)*64 + ee] - smM[ee]) * smR[ee];
    }
    __syncthreads();

    // pixels owned by this g: (y,x) with y=(g/5+3)%5+5a, x=(g%5+3)%5+5b
    int y0 = (g/5 + 3) % 5, x0 = (g%5 + 3) % 5;
    int ny = (21 - y0 + 4) / 5, nx = (21 - x0 + 4) / 5;
    int npix = ny * nx;

    for (int p0 = 0; p0 < npix; p0 += 4) {
        int p = p0 + ps;
        bool pv = p < npix;
        int yy = 0, xx = 0;
        if (pv) { int a = p / nx, bb = p % nx; yy = y0 + 5*a; xx = x0 + 5*bb; }
        float svv = 0.f;
        if (pv && yy >= 2 && xx >= 2)
            svv = v[b*BVO + e*441 + (yy-2)*21 + (xx-2)];   // lane e <-> channel cv
        sv[ps][e] = svv;
        __syncthreads();
        if (pv) {
            float vt = 0.f;
            #pragma unroll
            for (int cv = 0; cv < 64; ++cv) vt += sv[ps][cv] * wT[cv*64 + e];
            int R = yy + 2, Cc = xx + 2;
            float kt = (R < 21 && Cc < 21) ? k1[b*BVO + (R*21 + Cc)*64 + e] : 0.f;
            out[b*BVO + e*441 + yy*21 + xx] = kt + vt;
        }
        __syncthreads();
    }
}

extern "C" void kernel_launch(void* const* d_in, const int* in_sizes, int n_in,
                              void* d_out, int out_size, void* d_ws, size_t ws_size,
                              hipStream_t stream) {
    const float* x        = (const float*)d_in[0];
    const float* wk       = (const float*)d_in[1];
    const float* bk       = (const float*)d_in[2];
    const float* w1       = (const float*)d_in[3];
    const float* bn_gamma = (const float*)d_in[4];
    const float* bn_beta  = (const float*)d_in[5];
    const float* bn_mean  = (const float*)d_in[6];
    const float* bn_var   = (const float*)d_in[7];
    const float* w2       = (const float*)d_in[8];
    const float* b2       = (const float*)d_in[9];
    const float* wv       = (const float*)d_in[10];
    const float* bv       = (const float*)d_in[11];

    float* out     = (float*)d_out;
    float* k1      = (float*)d_ws;            // 56448
    float* v       = k1 + 56448;              // 56448
    float* att1g   = v + 56448;               // 80000
    float* att2c   = att1g + 80000;           // 406400
    float* pm      = att2c + 406400;          // 25600
    float* pz      = pm + 25600;              // 25600

    hipLaunchKernelGGL(prep_kernel, dim3(1010), dim3(64), 0, stream,
                       x, wk, bk, wv, bv, k1, v);
    hipLaunchKernelGGL(att1_kernel, dim3(50), dim3(256), 0, stream,
                       x, k1, w1, bn_gamma, bn_beta, bn_mean, bn_var, att1g);
    hipLaunchKernelGGL(att2_kernel, dim3(400), dim3(256), 0, stream,
                       att1g, w2, b2, att2c, pm, pz);
    hipLaunchKernelGGL(out_kernel, dim3(50), dim3(256), 0, stream,
                       k1, v, att2c, pm, pz, out);
}